// Round 1
// 820.274 us; speedup vs baseline: 1.3182x; 1.3182x over previous
//
#include <hip/hip_runtime.h>

typedef unsigned short ushort_t;
typedef unsigned int uint32;

#define SCALE_F 0.08838834764831845f

using bf16x8 = __attribute__((ext_vector_type(8))) short;
using f32x4  = __attribute__((ext_vector_type(4))) float;
using u32x4  = __attribute__((ext_vector_type(4))) uint32;
using u32x2  = __attribute__((ext_vector_type(2))) uint32;

__device__ __forceinline__ float b2f(ushort_t h) {
  union { uint32 u; float f; } v; v.u = ((uint32)h) << 16; return v.f;
}
__device__ __forceinline__ ushort_t f2b(float f) {
  union { float f; uint32 u; } v; v.f = f;
  uint32 r = (v.u + 0x7fffu + ((v.u >> 16) & 1u)) >> 16;
  return (ushort_t)r;
}
// pack two fp32 -> u32 of two bf16 (round-half-up)
__device__ __forceinline__ uint32 pk2(float a, float b) {
  union { float f; uint32 u; } x, y; x.f = a; y.f = b;
  return __builtin_amdgcn_perm(y.u + 0x8000u, x.u + 0x8000u, 0x07060302u);
}
__device__ __forceinline__ void gl2lds16(const void* g, void* l) {
  __builtin_amdgcn_global_load_lds(
      (const __attribute__((address_space(1))) uint32*)g,
      (__attribute__((address_space(3))) uint32*)l, 16, 0, 0);
}

constexpr int LDP = 40;  // padded LDS leading dim (fallback fp32-staging path)

// ============================================================================
// FAST PATH: pre-converted bf16 operands + global_load_lds m97-structure GEMM
// ============================================================================

// ---- x fp32 [4096][4096] -> bf16 same layout -------------------------------
__global__ __launch_bounds__(256)
void xconv(const float* __restrict__ x, ushort_t* __restrict__ xb) {
  size_t i = ((size_t)blockIdx.x * 256 + threadIdx.x) * 8;
  f32x4 a = *(const f32x4*)&x[i];
  f32x4 b = *(const f32x4*)&x[i + 4];
  u32x4 p = {pk2(a[0], a[1]), pk2(a[2], a[3]), pk2(b[0], b[1]), pk2(b[2], b[3])};
  *(u32x4*)&xb[i] = p;
}

// ---- weight fp32 [4096][N] -> bf16 transposed [N][4096] --------------------
__global__ __launch_bounds__(256)
void wtrans(const float* __restrict__ src, ushort_t* __restrict__ dst, int N) {
  __shared__ float ts[32][33];
  int n0 = blockIdx.x * 32, k0 = blockIdx.y * 32;
  int tid = threadIdx.x;
  {
    int r = tid >> 3, c4 = (tid & 7) * 4;
    f32x4 v = *(const f32x4*)&src[(size_t)(k0 + r) * N + n0 + c4];
    ts[r][c4 + 0] = v[0]; ts[r][c4 + 1] = v[1];
    ts[r][c4 + 2] = v[2]; ts[r][c4 + 3] = v[3];
  }
  __syncthreads();
  int rn = tid >> 3, ck = (tid & 7) * 4;
  u32x2 p = {pk2(ts[ck + 0][rn], ts[ck + 1][rn]),
             pk2(ts[ck + 2][rn], ts[ck + 3][rn])};
  *(u32x2*)&dst[(size_t)(n0 + rn) * 4096 + k0 + ck] = p;
}

// ---- bf16 GEMM core: 128x128 tile, BK=32, global_load_lds width-16 ---------
// As/Bs: [128][32] bf16 LINEAR (8 KB each; unpadded -> fragment read is a
// contiguous 1024B/wave sweep, conflict-free, and gl2lds dest is linear).
// AMODE 0: A row-major bf16 [M][4096].
// AMODE 1: A attn-tiled bf16 [b][h][qb][dgrp4][row64][32] (K=4096 implied).
// B: row-major bf16 [N][4096] (pre-transposed weights).
template <int AMODE>
__device__ __forceinline__ void gemm_core_bf(const ushort_t* __restrict__ A,
                                             const ushort_t* __restrict__ B,
                                             int m0, int n0, ushort_t* As,
                                             ushort_t* Bs, f32x4 acc[4][4]) {
  const int K = 4096;
  int tid = threadIdx.x;
  int lane = tid & 63, w = tid >> 6, q = lane >> 4, cl = lane & 15;
  int wr = (w >> 1) * 64, wc = (w & 1) * 64;
  int wub = (tid & 192) * 8;  // wave-uniform LDS slot base (ushorts)
  for (int k0 = 0; k0 < K; k0 += 32) {
    __syncthreads();  // all waves done reading LDS of previous K-step
#pragma unroll
    for (int i = 0; i < 2; ++i) {
      int slot = i * 256 + tid;       // 512 slots x 16B = 128 rows x 32 bf16
      int r = slot >> 2, c = slot & 3;
      const ushort_t* ga;
      if (AMODE == 0) {
        ga = A + (size_t)(m0 + r) * K + k0 + c * 8;
      } else {
        int m = m0 + r, bb = m >> 11, s = m & 2047;
        int k = k0 + c * 8;
        int hh = k >> 7, dg = (k >> 5) & 3;
        ga = A + ((((size_t)(bb * 32 + hh) * 32 + (s >> 6)) * 4 + dg) * 64 +
                  (s & 63)) * 32 + (k & 31);
      }
      gl2lds16(ga, As + i * 2048 + wub);
      gl2lds16(B + (size_t)(n0 + r) * K + k0 + c * 8, Bs + i * 2048 + wub);
    }
    __syncthreads();  // vmcnt(0) drain: tiles resident
    bf16x8 af[4], bfr[4];
#pragma unroll
    for (int rt = 0; rt < 4; ++rt)
      af[rt] = *(const bf16x8*)&As[(wr + rt * 16 + cl) * 32 + q * 8];
#pragma unroll
    for (int ct = 0; ct < 4; ++ct)
      bfr[ct] = *(const bf16x8*)&Bs[(wc + ct * 16 + cl) * 32 + q * 8];
#pragma unroll
    for (int rt = 0; rt < 4; ++rt)
#pragma unroll
      for (int ct = 0; ct < 4; ++ct)
        acc[rt][ct] = __builtin_amdgcn_mfma_f32_16x16x32_bf16(
            af[rt], bfr[ct], acc[rt][ct], 0, 0, 0);
  }
}

// ---- fused QKV GEMM + RoPE + pre-tiling (fast path) ------------------------
// wt: [6144][4096] bf16 = concat(wq^T, wk^T, wv^T)
__global__ __launch_bounds__(256, 3)
void qkv_gemm(const ushort_t* __restrict__ xb, const ushort_t* __restrict__ wt,
              const float* __restrict__ fc, const float* __restrict__ fs,
              ushort_t* __restrict__ qg, ushort_t* __restrict__ kg,
              ushort_t* __restrict__ vg) {
  __shared__ ushort_t As[128 * 32];
  __shared__ ushort_t Bs[128 * 32];
  int n0 = blockIdx.x * 128, m0 = blockIdx.y * 128;
  f32x4 acc[4][4] = {};
  gemm_core_bf<0>(xb, wt, m0, n0, As, Bs, acc);
  int tid = threadIdx.x;
  int lane = tid & 63, w = tid >> 6, q = lane >> 4, cl = lane & 15;
  int wr = (w >> 1) * 64, wc = (w & 1) * 64;
  if (n0 < 5120) {
    // Q or K: rope via pair-exchange, then tiled scatter
    ushort_t* dst = (n0 < 4096) ? qg : kg;
    int NHH = (n0 < 4096) ? 32 : 8;
    int nc = (n0 < 4096) ? n0 : n0 - 4096;
    for (int rt = 0; rt < 4; ++rt)
      for (int ct = 0; ct < 4; ++ct)
        for (int rg = 0; rg < 4; ++rg) {
          int row = m0 + wr + rt * 16 + q * 4 + rg;
          int b = row >> 11, s = row & 2047;
          int col = nc + wc + ct * 16 + cl;
          int hh = col >> 7, d = col & 127;
          float val = acc[rt][ct][rg];
          float par = __shfl_xor(val, 1);
          float cf = fc[(size_t)s * 64 + (d >> 1)];
          float sf = fs[(size_t)s * 64 + (d >> 1)];
          float o = val * cf + par * ((d & 1) ? sf : -sf);
          size_t off =
              ((((size_t)(b * NHH + hh) * 32 + (s >> 6)) * 4 + (d >> 5)) * 64 +
               (s & 63)) * 32 + (d & 31);
          dst[off] = f2b(o);
        }
  } else {
    // V: transposed tiled scatter
    int nc = n0 - 5120;
    for (int rt = 0; rt < 4; ++rt)
      for (int ct = 0; ct < 4; ++ct)
        for (int rg = 0; rg < 4; ++rg) {
          int row = m0 + wr + rt * 16 + q * 4 + rg;
          int b = row >> 11, s = row & 2047;
          int col = nc + wc + ct * 16 + cl;
          int kvh = col >> 7, d = col & 127;
          size_t off =
              ((((size_t)(b * 8 + kvh) * 32 + (s >> 6)) * 2 + ((s >> 5) & 1)) *
                   128 + d) * 32 + (s & 31);
          vg[off] = f2b(acc[rt][ct][rg]);
        }
  }
}

// ---- output GEMM (fast path): attn(tiled bf16) @ wo^T(bf16) -> out fp32 ----
__global__ __launch_bounds__(256, 3)
void out_gemm(const ushort_t* __restrict__ attn,
              const ushort_t* __restrict__ wot, float* __restrict__ out) {
  __shared__ ushort_t As[128 * 32];
  __shared__ ushort_t Bs[128 * 32];
  int n0 = blockIdx.x * 128, m0 = blockIdx.y * 128;
  f32x4 acc[4][4] = {};
  gemm_core_bf<1>(attn, wot, m0, n0, As, Bs, acc);
  int tid = threadIdx.x;
  int lane = tid & 63, w = tid >> 6, q = lane >> 4, cl = lane & 15;
  int wr = (w >> 1) * 64, wc = (w & 1) * 64;
  for (int rt = 0; rt < 4; ++rt)
    for (int ct = 0; ct < 4; ++ct)
      for (int rg = 0; rg < 4; ++rg) {
        int row = m0 + wr + rt * 16 + q * 4 + rg;
        int col = n0 + wc + ct * 16 + cl;
        out[(size_t)row * 4096 + col] = acc[rt][ct][rg];
      }
}

// ============================================================================
// FALLBACK PATH (workspace < 128 MiB): previous verified fp32-staging kernels
// ============================================================================

template <int AMODE>
__device__ __forceinline__ void gemm_core_cvt(const void* __restrict__ A,
                                              const float* __restrict__ B, int K,
                                              int NB, int m0, int nb0,
                                              ushort_t* As, ushort_t* Bs,
                                              f32x4 acc[4][4]) {
  int tid = threadIdx.x;
  int lane = tid & 63, w = tid >> 6, q = lane >> 4, cl = lane & 15;
  int wr = (w >> 1) * 64, wc = (w & 1) * 64;
  int ar = tid >> 1, ah = tid & 1;
  int bn = tid & 127, bh = tid >> 7;
  for (int k0 = 0; k0 < K; k0 += 32) {
    __syncthreads();
    if (AMODE == 0) {
      const float* ap = &((const float*)A)[(size_t)(m0 + ar) * K + k0 + ah * 16];
      f32x4 a0 = *(const f32x4*)(ap + 0);
      f32x4 a1 = *(const f32x4*)(ap + 4);
      f32x4 a2 = *(const f32x4*)(ap + 8);
      f32x4 a3 = *(const f32x4*)(ap + 12);
      u32x4 p0 = {pk2(a0[0], a0[1]), pk2(a0[2], a0[3]), pk2(a1[0], a1[1]),
                  pk2(a1[2], a1[3])};
      u32x4 p1 = {pk2(a2[0], a2[1]), pk2(a2[2], a2[3]), pk2(a3[0], a3[1]),
                  pk2(a3[2], a3[3])};
      *(u32x4*)&As[ar * LDP + ah * 16] = p0;
      *(u32x4*)&As[ar * LDP + ah * 16 + 8] = p1;
    } else {
      int m = m0 + ar, bb = m >> 11, s = m & 2047;
      int k = k0 + ah * 16;
      int hh = k >> 7, dg = (k >> 5) & 3, el = k & 31;
      size_t off =
          ((((size_t)(bb * 32 + hh) * 32 + (s >> 6)) * 4 + dg) * 64 +
           (s & 63)) * 32 + el;
      const ushort_t* ap = (const ushort_t*)A + off;
      u32x4 v0 = *(const u32x4*)(ap + 0);
      u32x4 v1 = *(const u32x4*)(ap + 8);
      *(u32x4*)&As[ar * LDP + ah * 16] = v0;
      *(u32x4*)&As[ar * LDP + ah * 16 + 8] = v1;
    }
    {
      float bv[16];
#pragma unroll
      for (int j = 0; j < 16; ++j)
        bv[j] = B[(size_t)(k0 + bh * 16 + j) * NB + nb0 + bn];
      u32x4 p0 = {pk2(bv[0], bv[1]), pk2(bv[2], bv[3]), pk2(bv[4], bv[5]),
                  pk2(bv[6], bv[7])};
      u32x4 p1 = {pk2(bv[8], bv[9]), pk2(bv[10], bv[11]), pk2(bv[12], bv[13]),
                  pk2(bv[14], bv[15])};
      *(u32x4*)&Bs[bn * LDP + bh * 16] = p0;
      *(u32x4*)&Bs[bn * LDP + bh * 16 + 8] = p1;
    }
    __syncthreads();
    bf16x8 af[4], bfr[4];
    for (int rt = 0; rt < 4; ++rt)
      af[rt] = *(const bf16x8*)&As[(wr + rt * 16 + cl) * LDP + q * 8];
    for (int ct = 0; ct < 4; ++ct)
      bfr[ct] = *(const bf16x8*)&Bs[(wc + ct * 16 + cl) * LDP + q * 8];
    for (int rt = 0; rt < 4; ++rt)
      for (int ct = 0; ct < 4; ++ct)
        acc[rt][ct] = __builtin_amdgcn_mfma_f32_16x16x32_bf16(
            af[rt], bfr[ct], acc[rt][ct], 0, 0, 0);
  }
}

__global__ __launch_bounds__(256, 3)
void qkv_gemm_cvt(const float* __restrict__ x, const float* __restrict__ wq,
                  const float* __restrict__ wk, const float* __restrict__ wv,
                  const float* __restrict__ fc, const float* __restrict__ fs,
                  ushort_t* __restrict__ qg, ushort_t* __restrict__ kg,
                  ushort_t* __restrict__ vg) {
  __shared__ ushort_t As[128 * LDP];
  __shared__ ushort_t Bs[128 * LDP];
  int n0 = blockIdx.x * 128, m0 = blockIdx.y * 128;
  const float* Bp; int NB, nc;
  if (n0 < 4096)      { Bp = wq; NB = 4096; nc = n0; }
  else if (n0 < 5120) { Bp = wk; NB = 1024; nc = n0 - 4096; }
  else                { Bp = wv; NB = 1024; nc = n0 - 5120; }
  f32x4 acc[4][4] = {};
  gemm_core_cvt<0>(x, Bp, 4096, NB, m0, nc, As, Bs, acc);
  int tid = threadIdx.x;
  int lane = tid & 63, w = tid >> 6, q = lane >> 4, cl = lane & 15;
  int wr = (w >> 1) * 64, wc = (w & 1) * 64;
  if (n0 < 5120) {
    ushort_t* dst = (n0 < 4096) ? qg : kg;
    int NHH = (n0 < 4096) ? 32 : 8;
    for (int rt = 0; rt < 4; ++rt)
      for (int ct = 0; ct < 4; ++ct)
        for (int rg = 0; rg < 4; ++rg) {
          int row = m0 + wr + rt * 16 + q * 4 + rg;
          int b = row >> 11, s = row & 2047;
          int col = nc + wc + ct * 16 + cl;
          int hh = col >> 7, d = col & 127;
          float val = acc[rt][ct][rg];
          float par = __shfl_xor(val, 1);
          float cf = fc[(size_t)s * 64 + (d >> 1)];
          float sf = fs[(size_t)s * 64 + (d >> 1)];
          float o = val * cf + par * ((d & 1) ? sf : -sf);
          size_t off =
              ((((size_t)(b * NHH + hh) * 32 + (s >> 6)) * 4 + (d >> 5)) * 64 +
               (s & 63)) * 32 + (d & 31);
          dst[off] = f2b(o);
        }
  } else {
    for (int rt = 0; rt < 4; ++rt)
      for (int ct = 0; ct < 4; ++ct)
        for (int rg = 0; rg < 4; ++rg) {
          int row = m0 + wr + rt * 16 + q * 4 + rg;
          int b = row >> 11, s = row & 2047;
          int col = nc + wc + ct * 16 + cl;
          int kvh = col >> 7, d = col & 127;
          size_t off =
              ((((size_t)(b * 8 + kvh) * 32 + (s >> 6)) * 2 + ((s >> 5) & 1)) *
                   128 + d) * 32 + (s & 31);
          vg[off] = f2b(acc[rt][ct][rg]);
        }
  }
}

__global__ __launch_bounds__(256, 3)
void out_gemm_cvt(const ushort_t* __restrict__ attn,
                  const float* __restrict__ wo, float* __restrict__ out) {
  __shared__ ushort_t As[128 * LDP];
  __shared__ ushort_t Bs[128 * LDP];
  int n0 = blockIdx.x * 128, m0 = blockIdx.y * 128;
  f32x4 acc[4][4] = {};
  gemm_core_cvt<1>(attn, wo, 4096, 4096, m0, n0, As, Bs, acc);
  int tid = threadIdx.x;
  int lane = tid & 63, w = tid >> 6, q = lane >> 4, cl = lane & 15;
  int wr = (w >> 1) * 64, wc = (w & 1) * 64;
  for (int rt = 0; rt < 4; ++rt)
    for (int ct = 0; ct < 4; ++ct)
      for (int rg = 0; rg < 4; ++rg) {
        int row = m0 + wr + rt * 16 + q * 4 + rg;
        int col = n0 + wc + ct * 16 + cl;
        out[(size_t)row * 4096 + col] = acc[rt][ct][rg];
      }
}

// ---- flash attention: Q in regs, K/V double-buffered DMA, 1 barrier/tile ---
__device__ __forceinline__ void stage_tile(const ushort_t* src, ushort_t* dst,
                                           int tid) {
  for (int cc = 0; cc < 4; ++cc)
    gl2lds16(src + (size_t)(cc * 256 + tid) * 8,
             dst + (size_t)(cc * 256 + (tid & 192)) * 8);
}

__global__ __launch_bounds__(256, 2)
void flash_attn(ushort_t* __restrict__ qg, const ushort_t* __restrict__ kg,
                const ushort_t* __restrict__ vg) {
  __shared__ ushort_t Ks[2][8192];  // [dgrp4][row64][32]
  __shared__ ushort_t Vs[2][8192];  // [jgrp2][d128][j32]
  __shared__ ushort_t Ps[4096];     // per-wave [jgrp2][16][32]
  int tid = threadIdx.x;
  int w = tid >> 6, lane = tid & 63, q = lane >> 4, cl = lane & 15;
  int idx = blockIdx.x;
  int qb = 31 - (idx >> 6);  // heavy blocks first
  int bh = idx & 63;
  int b = bh >> 5, h = bh & 31, kvh = h >> 2;

  ushort_t* qt = qg + ((size_t)(b * 32 + h) * 32 + qb) * 8192;
  bf16x8 aq[4];
  for (int ks = 0; ks < 4; ++ks)
    aq[ks] = *(const bf16x8*)&qt[ks * 2048 + (w * 16 + cl) * 32 + q * 8];

  const ushort_t* kb = kg + ((size_t)(b * 8 + kvh) * 32) * 8192;
  const ushort_t* vb = vg + ((size_t)(b * 8 + kvh) * 32) * 8192;
  stage_tile(kb, Ks[0], tid);
  stage_tile(vb, Vs[0], tid);

  f32x4 oacc[8] = {};
  float m_i[4], l_i[4];
  for (int rg = 0; rg < 4; ++rg) { m_i[rg] = -3e30f; l_i[rg] = 0.f; }

  for (int jb = 0; jb <= qb; ++jb) {
    __syncthreads();
    int cur = jb & 1, nxt = (jb + 1) & 1;
    int jn = (jb + 1 > qb) ? qb : jb + 1;
    stage_tile(kb + (size_t)jn * 8192, Ks[nxt], tid);
    stage_tile(vb + (size_t)jn * 8192, Vs[nxt], tid);
    f32x4 sacc[4] = {};
    for (int ks = 0; ks < 4; ++ks)
      for (int ct = 0; ct < 4; ++ct) {
        bf16x8 bk =
            *(const bf16x8*)&Ks[cur][ks * 2048 + (ct * 16 + cl) * 32 + q * 8];
        sacc[ct] =
            __builtin_amdgcn_mfma_f32_16x16x32_bf16(aq[ks], bk, sacc[ct], 0, 0, 0);
      }
    float pv[4][4], mt[4];
    bool diag = (jb == qb);
    for (int rg = 0; rg < 4; ++rg) mt[rg] = -3e30f;
    for (int ct = 0; ct < 4; ++ct)
      for (int rg = 0; rg < 4; ++rg) {
        float sv = sacc[ct][rg] * SCALE_F;
        if (diag) {
          int rrow = w * 16 + q * 4 + rg;
          int ccol = ct * 16 + cl;
          if (ccol > rrow) sv = -3e30f;
        }
        pv[ct][rg] = sv;
        mt[rg] = fmaxf(mt[rg], sv);
      }
    for (int off = 1; off < 16; off <<= 1)
      for (int rg = 0; rg < 4; ++rg)
        mt[rg] = fmaxf(mt[rg], __shfl_xor(mt[rg], off));
    float alpha[4], rs[4];
    for (int rg = 0; rg < 4; ++rg) {
      float mn = fmaxf(m_i[rg], mt[rg]);
      alpha[rg] = __expf(m_i[rg] - mn);
      m_i[rg] = mn;
      rs[rg] = 0.f;
    }
    for (int ct = 0; ct < 4; ++ct)
      for (int rg = 0; rg < 4; ++rg) {
        float p = __expf(pv[ct][rg] - m_i[rg]);
        pv[ct][rg] = p;
        rs[rg] += p;
      }
    for (int off = 1; off < 16; off <<= 1)
      for (int rg = 0; rg < 4; ++rg) rs[rg] += __shfl_xor(rs[rg], off);
    for (int rg = 0; rg < 4; ++rg) l_i[rg] = l_i[rg] * alpha[rg] + rs[rg];
    for (int nt = 0; nt < 8; ++nt)
      for (int rg = 0; rg < 4; ++rg) oacc[nt][rg] *= alpha[rg];
    for (int ct = 0; ct < 4; ++ct)
      for (int rg = 0; rg < 4; ++rg) {
        int off_ = w * 1024 + (ct >> 1) * 512 + (q * 4 + rg) * 32 +
                   (ct & 1) * 16 + cl;
        Ps[off_] = f2b(pv[ct][rg]);
      }
    for (int ks2 = 0; ks2 < 2; ++ks2) {
      bf16x8 pa = *(const bf16x8*)&Ps[w * 1024 + ks2 * 512 + cl * 32 + q * 8];
      for (int nt = 0; nt < 8; ++nt) {
        bf16x8 bv =
            *(const bf16x8*)&Vs[cur][ks2 * 4096 + (nt * 16 + cl) * 32 + q * 8];
        oacc[nt] =
            __builtin_amdgcn_mfma_f32_16x16x32_bf16(pa, bv, oacc[nt], 0, 0, 0);
      }
    }
  }
  for (int nt = 0; nt < 8; ++nt)
    for (int rg = 0; rg < 4; ++rg) {
      float v = oacc[nt][rg] / l_i[rg];
      int rowt = w * 16 + q * 4 + rg;
      int d = nt * 16 + cl;
      qt[(d >> 5) * 2048 + rowt * 32 + (d & 31)] = f2b(v);
    }
}

extern "C" void kernel_launch(void* const* d_in, const int* in_sizes, int n_in,
                              void* d_out, int out_size, void* d_ws,
                              size_t ws_size, hipStream_t stream) {
  const float* x  = (const float*)d_in[0];
  const float* fc = (const float*)d_in[1];
  const float* fs = (const float*)d_in[2];
  // d_in[3] = mask (causal hardcoded), d_in[8] = positions (unused)
  const float* wq = (const float*)d_in[4];
  const float* wk = (const float*)d_in[5];
  const float* wv = (const float*)d_in[6];
  const float* wo = (const float*)d_in[7];
  ushort_t* ws = (ushort_t*)d_ws;

  // workspace (fast path, 128 MiB total):
  //   qg 32 MiB | kg 8 | vg 8 | wt (= [wq^T; wk^T; wv^T] bf16) 48 | xb 32
  //   xb is dead after qkv_gemm and is reused to hold wo^T for out_gemm.
  ushort_t* qg = ws;
  ushort_t* kg = qg + (size_t)4096 * 4096;
  ushort_t* vg = kg + (size_t)4096 * 1024;

  if (ws_size >= (size_t)128 * 1024 * 1024) {
    ushort_t* wt = vg + (size_t)4096 * 1024;
    ushort_t* xb = wt + (size_t)6144 * 4096;
    xconv<<<8192, 256, 0, stream>>>(x, xb);
    wtrans<<<dim3(128, 128), 256, 0, stream>>>(wq, wt, 4096);
    wtrans<<<dim3(32, 128), 256, 0, stream>>>(wk, wt + (size_t)4096 * 4096, 1024);
    wtrans<<<dim3(32, 128), 256, 0, stream>>>(wv, wt + (size_t)5120 * 4096, 1024);
    qkv_gemm<<<dim3(48, 32), 256, 0, stream>>>(xb, wt, fc, fs, qg, kg, vg);
    wtrans<<<dim3(128, 128), 256, 0, stream>>>(wo, xb, 4096);  // xb -> wo^T
    flash_attn<<<2048, 256, 0, stream>>>(qg, kg, vg);
    out_gemm<<<dim3(32, 32), 256, 0, stream>>>(qg, xb, (float*)d_out);
  } else {
    // fallback: previous verified path (48 MiB workspace)
    qkv_gemm_cvt<<<dim3(48, 32), 256, 0, stream>>>(x, wq, wk, wv, fc, fs, qg,
                                                   kg, vg);
    flash_attn<<<2048, 256, 0, stream>>>(qg, kg, vg);
    out_gemm_cvt<<<dim3(32, 32), 256, 0, stream>>>(qg, wo, (float*)d_out);
  }
}